// Round 2
// baseline (447.320 us; speedup 1.0000x reference)
//
#include <hip/hip_runtime.h>

// VQEmbedding forward (TRAINING=True):
//   z_e_x [32,256,64,64] f32, codebook [512,256] f32, labels [32] i32
//   out = concat(z_q_x, z_q_x_bar), each [32,256,64,64] f32 — both equal
//   codebook[argmin] in the forward pass (x+(c-x) roundoff ~4e-7 << thr).
//
// The numpy reference computes distances IN FP32:
//   dist = fl( fl(in_sqr + cb_sqr_k) - 2*dot_k ),  dot = sequential-k FMA (BLAS)
// with in_sqr ~ 256 -> quantization at ulp(256)~3e-5, ties -> lowest index.
// We emulate that arithmetic bit-exactly instead of computing the true argmin:
//   - dot: ascending-d fp32 FMA chain (== sgemm microkernel accumulation)
//   - in_sqr: fp64 -> fp32 (grid-translation invariance makes exact bits moot)
//   - cb_sqr: fp64 -> fp32 (<=1 ulp of 3e-4; flip prob ~1e-5, negligible)
//   - dist: fmaf(-2, acc, T) == fl(T - fl(2*acc)) since fl(2*acc) is exact
//
// Class partition of round(linspace(-0.5, 9.49, 502)) is contiguous ranges;
// boundary margins >= 1e-3 >> fp32 noise, so hardcode the start table.
// Shared tail codes 502..511 are always masked (TRAINING).

#define D       256
#define KCODES  512
#define HW      4096
#define BATCH   32
#define NPTS    (BATCH * HW)   // 131072
#define MAXC    51             // max codes per class

__constant__ int c_cls_start[11] = {0, 51, 101, 151, 201, 251, 301, 352, 402, 452, 502};

// Prep: cbT[d][k] = cb[k][d]  (per-d class slice contiguous -> scalar loads),
//       cbs[k] = fl32( fp64 sum_d cb[k][d]^2 )
__global__ __launch_bounds__(256) void prep_kernel(const float* __restrict__ cb,
                                                   float* __restrict__ cbT,
                                                   float* __restrict__ cbs) {
    const int k = blockIdx.x;   // 0..511
    const int d = threadIdx.x;  // 0..255
    float v = cb[k * D + d];
    cbT[(size_t)d * KCODES + k] = v;
    __shared__ double red[256];
    red[d] = (double)v * (double)v;
    __syncthreads();
    for (int s = 128; s > 0; s >>= 1) {
        if (d < s) red[d] += red[d + s];
        __syncthreads();
    }
    if (d == 0) cbs[k] = (float)red[0];
}

__global__ __launch_bounds__(256) void vq_kernel(const float* __restrict__ z,
                                                 const int* __restrict__ labels,
                                                 const float* __restrict__ cbT,
                                                 const float* __restrict__ cbs,
                                                 float* __restrict__ out) {
    const int b   = blockIdx.x >> 4;                       // 16 blocks per image
    const int hw  = ((blockIdx.x & 15) << 8) | threadIdx.x;
    const int lab = __builtin_amdgcn_readfirstlane(labels[b]);
    const int c0  = c_cls_start[lab];
    const int cnt = c_cls_start[lab + 1] - c0;             // 50 or 51

    const float* __restrict__ xp = z + (size_t)b * (D * HW) + hw;  // x[d] = xp[d*HW]

    float acc[MAXC];
#pragma unroll
    for (int k = 0; k < MAXC; ++k) acc[k] = 0.0f;

    double xsq = 0.0;  // ||x||^2 in fp64 (rounded to fp32 at the end)

    // x prefetch pipeline, depth 4 (one d-chunk ahead of the FMA block)
    float xb[4];
#pragma unroll
    for (int i = 0; i < 4; ++i) xb[i] = xp[(size_t)i * HW];

    for (int d = 0; d < D; d += 4) {
        float xn[4];
#pragma unroll
        for (int i = 0; i < 4; ++i) {
            int dn = (d + 4 + i) & (D - 1);  // wrap on last chunk (harmless reload)
            xn[i] = xp[(size_t)dn * HW];
        }
#pragma unroll
        for (int i = 0; i < 4; ++i) {
            const float* __restrict__ wd = cbT + (size_t)(d + i) * KCODES + c0;
            const float x = xb[i];
            xsq = fma((double)x, (double)x, xsq);
#pragma unroll
            for (int k = 0; k < MAXC; ++k)
                acc[k] = fmaf(x, wd[k], acc[k]);  // ascending-d fp32 FMA chain == sgemm
        }
#pragma unroll
        for (int i = 0; i < 4; ++i) xb[i] = xn[i];
    }

    // Emulated reference distance: dist = fl( fl(insq + cbs_k) - 2*acc_k ),
    // argmin with first-index tie-break (strict <, ascending k).
    const float insq = (float)xsq;
    float best = __builtin_inff();
    int i1 = c0;
#pragma unroll
    for (int k = 0; k < MAXC; ++k) {
        if (k < cnt) {
            float T    = insq + cbs[c0 + k];       // fp32 add, round-nearest-even
            float dist = fmaf(-2.0f, acc[k], T);   // == fl(T - 2*acc), single rounding
            if (dist < best) { best = dist; i1 = c0 + k; }
        }
    }

    // Epilogue: out0 = out1 = codebook[i1] scattered to [B,D,H,W]
    float* __restrict__ o0 = out + (size_t)b * (D * HW) + hw;
    float* __restrict__ o1 = o0 + (size_t)NPTS * D;
    const int ci = i1;
    for (int d = 0; d < D; ++d) {
        float v = cbT[(size_t)d * KCODES + ci];  // lanes within 204B window -> L1
        o0[(size_t)d * HW] = v;
        o1[(size_t)d * HW] = v;
    }
}

extern "C" void kernel_launch(void* const* d_in, const int* in_sizes, int n_in,
                              void* d_out, int out_size, void* d_ws, size_t ws_size,
                              hipStream_t stream) {
    const float* z      = (const float*)d_in[0];
    const float* cb     = (const float*)d_in[1];
    const int*   labels = (const int*)d_in[2];
    float* out = (float*)d_out;

    float* cbT = (float*)d_ws;              // 256*512 f32 = 512 KB
    float* cbs = cbT + (size_t)D * KCODES;  // 512 f32

    hipLaunchKernelGGL(prep_kernel, dim3(KCODES), dim3(D), 0, stream, cb, cbT, cbs);
    hipLaunchKernelGGL(vq_kernel, dim3(NPTS / 256), dim3(256), 0, stream,
                       z, labels, cbT, cbs, out);
}

// Round 3
// 404.223 us; speedup vs baseline: 1.1066x; 1.1066x over previous
//
#include <hip/hip_runtime.h>

// VQEmbedding forward (TRAINING=True):
//   z_e_x [32,256,64,64] f32, codebook [512,256] f32, labels [32] i32
//   out = concat(z_q_x, z_q_x_bar), each [32,256,64,64] f32 — both equal
//   codebook[argmin] in the forward pass (x+(c-x) roundoff ~4e-7 << thr).
//
// The numpy reference computes distances IN FP32:
//   dist = fl( fl(in_sqr + cb_sqr_k) - 2*dot_k ),  dot = sequential-k FMA (BLAS)
// We emulate that arithmetic bit-exactly (same as Round 2, which passed):
//   - dot: ascending-d fp32 FMA chain per (point, code)
//   - in_sqr: fp64 ascending-d fma -> fp32
//   - cb_sqr: fp64 -> fp32
//   - dist: fmaf(-2, acc, T); strict < ascending k == first-index tie-break
//
// R3 restructure: occupancy was grid-capped at 25% (1 thread/point = 2048
// waves). Now: block = 4 waves / 64 points; wave w handles 13 codes
// (wave-uniform -> s_load SGPR operands) for all 64 points. 8192 waves total
// = 100% occupancy. LDS combine (2 KB) for the cross-wave argmin.

#define D       256
#define KCODES  512
#define HW      4096
#define BATCH   32
#define NPTS    (BATCH * HW)   // 131072
#define WPW     13             // codes per wave (4*13=52 >= max class size 51)

__constant__ int c_cls_start[11] = {0, 51, 101, 151, 201, 251, 301, 352, 402, 452, 502};

// Prep: cbT[d][k] = cb[k][d]  (per-d class slice contiguous -> scalar loads),
//       cbs[k] = fl32( fp64 sum_d cb[k][d]^2 )
__global__ __launch_bounds__(256) void prep_kernel(const float* __restrict__ cb,
                                                   float* __restrict__ cbT,
                                                   float* __restrict__ cbs) {
    const int k = blockIdx.x;   // 0..511
    const int d = threadIdx.x;  // 0..255
    float v = cb[k * D + d];
    cbT[(size_t)d * KCODES + k] = v;
    __shared__ double red[256];
    red[d] = (double)v * (double)v;
    __syncthreads();
    for (int s = 128; s > 0; s >>= 1) {
        if (d < s) red[d] += red[d + s];
        __syncthreads();
    }
    if (d == 0) cbs[k] = (float)red[0];
}

__global__ __launch_bounds__(256) void vq_kernel(const float* __restrict__ z,
                                                 const int* __restrict__ labels,
                                                 const float* __restrict__ cbT,
                                                 const float* __restrict__ cbs,
                                                 float* __restrict__ out) {
    const int lane = threadIdx.x & 63;
    const int w    = __builtin_amdgcn_readfirstlane(threadIdx.x >> 6);  // wave id 0..3
    const int b    = blockIdx.x >> 6;                  // 64 blocks per image
    const int hw   = ((blockIdx.x & 63) << 6) | lane;  // this lane's point
    const int lab  = __builtin_amdgcn_readfirstlane(labels[b]);
    const int c0   = c_cls_start[lab];
    const int cnt  = c_cls_start[lab + 1] - c0;        // 50 or 51
    const int kbase = c0 + w * WPW;                    // wave-uniform (SGPR)
    const int myn   = min(WPW, cnt - w * WPW);         // 13,13,13,{11|12}

    const float* __restrict__ xp = z + (size_t)b * (D * HW) + hw;  // x[d] = xp[d*HW]

    float acc[WPW];
#pragma unroll
    for (int j = 0; j < WPW; ++j) acc[j] = 0.0f;

    double xsq = 0.0;  // ||x||^2 in fp64, ascending d (identical to R2)

    // x prefetch pipeline, depth 4
    float xb[4];
#pragma unroll
    for (int i = 0; i < 4; ++i) xb[i] = xp[(size_t)i * HW];

    for (int d = 0; d < D; d += 4) {
        float xn[4];
#pragma unroll
        for (int i = 0; i < 4; ++i) {
            int dn = (d + 4 + i) & (D - 1);  // wrap on last chunk (harmless reload)
            xn[i] = xp[(size_t)dn * HW];
        }
#pragma unroll
        for (int i = 0; i < 4; ++i) {
            // wave-uniform address -> scalar loads, SGPR FMA operand
            const float* __restrict__ wd = cbT + (size_t)(d + i) * KCODES + kbase;
            const float x = xb[i];
            xsq = fma((double)x, (double)x, xsq);
#pragma unroll
            for (int j = 0; j < WPW; ++j)
                acc[j] = fmaf(x, wd[j], acc[j]);  // ascending-d fp32 chain == sgemm
        }
#pragma unroll
        for (int i = 0; i < 4; ++i) xb[i] = xn[i];
    }

    // Emulated reference distance; local argmin over this wave's codes
    const float insq = (float)xsq;
    float best = __builtin_inff();
    int bi = kbase;
#pragma unroll
    for (int j = 0; j < WPW; ++j) {
        if (j < myn) {
            float T    = insq + cbs[kbase + j];    // fp32 add, RNE
            float dist = fmaf(-2.0f, acc[j], T);   // == fl(T - 2*acc)
            if (dist < best) { best = dist; bi = kbase + j; }
        }
    }

    // Cross-wave argmin via LDS (ascending w + strict < == lowest-index tie-break)
    __shared__ float sd[4][64];
    __shared__ int   si[4][64];
    sd[w][lane] = best;
    si[w][lane] = bi;
    __syncthreads();
    float fb = sd[0][lane];
    int   fi = si[0][lane];
#pragma unroll
    for (int w2 = 1; w2 < 4; ++w2) {
        float dv = sd[w2][lane];
        if (dv < fb) { fb = dv; fi = si[w2][lane]; }
    }

    // Epilogue: out0 = out1 = codebook[fi]; wave w writes d in [64w, 64w+64)
    float* __restrict__ o0 = out + (size_t)b * (D * HW) + hw;
    float* __restrict__ o1 = o0 + (size_t)NPTS * D;
    const int d0 = w * 64;
    for (int d = d0; d < d0 + 64; ++d) {
        float v = cbT[(size_t)d * KCODES + fi];  // gather within 204B window -> L1
        o0[(size_t)d * HW] = v;
        o1[(size_t)d * HW] = v;
    }
}

extern "C" void kernel_launch(void* const* d_in, const int* in_sizes, int n_in,
                              void* d_out, int out_size, void* d_ws, size_t ws_size,
                              hipStream_t stream) {
    const float* z      = (const float*)d_in[0];
    const float* cb     = (const float*)d_in[1];
    const int*   labels = (const int*)d_in[2];
    float* out = (float*)d_out;

    float* cbT = (float*)d_ws;              // 256*512 f32 = 512 KB
    float* cbs = cbT + (size_t)D * KCODES;  // 512 f32

    hipLaunchKernelGGL(prep_kernel, dim3(KCODES), dim3(D), 0, stream, cb, cbT, cbs);
    hipLaunchKernelGGL(vq_kernel, dim3(NPTS / 64), dim3(256), 0, stream,
                       z, labels, cbT, cbs, out);
}